// Round 16
// baseline (2342.501 us; speedup 1.0000x reference)
//
#include <hip/hip_runtime.h>
#include <stdint.h>

// RNNTextClassifier: B=64, S=512, E=H=512, NCLS=8
// Round 19: R18 base (proven 1718us) + PER-WAVE-QUARTER H path.
// Insight: wave (kq) only consumes h cols kq*128..+128 (publishers 2kq,
// 2kq+1). R18's B1 forced every wave to wait for ALL quarters' staging.
// R19: each wave polls+stages ITS quarter into a pair-shared LDS region
// (pair waves duplicate-stage identical data = benign race), then runs
// its H MFMAs immediately — NO barrier on the h path. Block-coupling
// only at B3 (inherent: finals reduce all quarters). Cost: 2x H-poll
// traffic (falsifiable via FETCH). bp on wave0's spin (lanes<8).
// in0/emb: R8 all-thread shape + lgkm-only B1 (emb prefetch stays in
// flight). Ring slot=s&3, tag=s&7, bp s-4, UC sc0 sc1, bounds(512,1).
// ws: hsl 1MB at offset 0 (memset to 0 each launch).

#define BB 64
#define SS 512
#define HH 512

typedef short bf16x8 __attribute__((ext_vector_type(8)));
typedef float f32x4 __attribute__((ext_vector_type(4)));
typedef int i32x4 __attribute__((ext_vector_type(4)));
typedef unsigned int u32;
typedef u32 u32x2 __attribute__((ext_vector_type(2)));

__device__ __forceinline__ unsigned short f2bf(float f) {
  uint32_t u = __builtin_bit_cast(uint32_t, f);
  u += 0x7FFFu + ((u >> 16) & 1u);
  return (unsigned short)(u >> 16);
}
__device__ __forceinline__ float bf2f(unsigned short h) {
  uint32_t u = ((uint32_t)h) << 16;
  return __builtin_bit_cast(float, u);
}
__device__ __forceinline__ int pack2(unsigned short a, unsigned short b) {
  return (int)(unsigned int)a | ((int)(unsigned int)b << 16);
}
__device__ __forceinline__ u32 hipack(u32 a, u32 b) {
  return (a >> 16) | (b & 0xFFFF0000u);
}
__device__ __forceinline__ u32 lopack(u32 a, u32 b) {
  return (a & 0xFFF8u) | ((b & 0xFFF8u) << 16);
}
__device__ __forceinline__ bool tag4(i32x4 v, u32 t) {
  u32 m = (((u32)v[0] ^ t) | ((u32)v[1] ^ t) | ((u32)v[2] ^ t) | ((u32)v[3] ^ t)) & 7u;
  return m == 0u;
}
__device__ __forceinline__ float fast_tanh(float v) {
  float a = __builtin_fabsf(v);
  float e = __expf(-2.0f * a);
  float t = (1.0f - e) / (1.0f + e);
  return __builtin_copysignf(t, v);
}

// LDS-only barrier: no vmcnt drain (protects LDS staging only).
#define BAR_LDS()                                            \
  do {                                                       \
    asm volatile("s_waitcnt lgkmcnt(0)" ::: "memory");       \
    __builtin_amdgcn_s_barrier();                            \
  } while (0)

#define UC_LOAD4(dst, ptr) \
  asm volatile("global_load_dwordx4 %0, %1, off sc0 sc1" : "=v"(dst) : "v"(ptr))
#define UC_LOAD1(dst, ptr) \
  asm volatile("global_load_dword %0, %1, off sc0 sc1" : "=v"(dst) : "v"(ptr))
#define UC_STORE2(ptr, v) \
  asm volatile("global_store_dwordx2 %0, %1, off sc0 sc1" ::"v"(ptr), "v"(v) : "memory")

__global__ __launch_bounds__(512, 1) void k_rnn(
    const int* __restrict__ x, const float* __restrict__ emb,
    const float* __restrict__ Wih0, const float* __restrict__ Whh0,
    const float* __restrict__ bih0, const float* __restrict__ bhh0,
    const float* __restrict__ Wih1, const float* __restrict__ Whh1,
    const float* __restrict__ bih1, const float* __restrict__ bhh1,
    u32* __restrict__ hsl) {
  const int tid = threadIdx.x;
  const int bid = blockIdx.x;
  const int layer = bid >> 5;  // 0 or 1
  const int lb = bid & 31;
  const int bg = lb >> 3;  // batch group (16 rows)
  const int c = lb & 7;    // hidden slice (64 dims)
  const int wid = tid >> 6;
  const int lane = tid & 63;
  const int kq = wid >> 1;  // K-quarter (0..3); pair (2kq,2kq+1) shares
  const int nh = wid & 1;   // N-half (32 cols)
  const int lr = lane >> 3;   // quarter-poll row 0..7 (and +8)
  const int lch = lane & 7;   // quarter-poll 16-u32 col chunk
  const int r_st = tid >> 5;  // in0 staging row 0..15
  const int ch = tid & 31;    // in0 staging 16-elem chunk

  __shared__ __align__(16) unsigned short s_in0[16 * 512];     // 16KB
  __shared__ __align__(16) unsigned short s_Hq_hi[4 * 16 * 128];  // 16KB
  __shared__ __align__(16) unsigned short s_Hq_lo[4 * 16 * 128];  // 16KB
  __shared__ __align__(16) float s_part[4 * 16 * 64];          // 16KB

  const float* Wih = layer ? Wih1 : Wih0;
  const float* Whh = layer ? Whh1 : Whh0;
  const float* bi = layer ? bih1 : bih0;
  const float* bh = layer ? bhh1 : bhh0;

  // ---- one-time: W fragments into VGPRs (mapping unchanged) ----
  bf16x8 wih[2][4], whhh[2][4], whhl[2][4];
  {
    const int r16 = lane & 15, kg = lane >> 4;
#pragma unroll
    for (int nt = 0; nt < 2; ++nt) {
#pragma unroll
      for (int kt = 0; kt < 4; ++kt) {
        int row = c * 64 + nh * 32 + nt * 16 + r16;
        int k0 = kq * 128 + kt * 32 + kg * 8;
        const float* p = Wih + row * 512 + k0;
        bf16x8 v;
#pragma unroll
        for (int j = 0; j < 8; ++j) v[j] = (short)f2bf(p[j]);
        wih[nt][kt] = v;
        const float* q = Whh + row * 512 + k0;
        bf16x8 vh, vl;
#pragma unroll
        for (int j = 0; j < 8; ++j) {
          float f = q[j];
          unsigned short h = f2bf(f);
          vh[j] = (short)h;
          vl[j] = (short)f2bf(f - bf2f(h));
        }
        whhh[nt][kt] = vh;
        whhl[nt][kt] = vl;
      }
    }
  }
  float biasv0, biasv1;
  {
    int na = (tid & 31) * 2;
    biasv0 = bi[c * 64 + na] + bh[c * 64 + na];
    biasv1 = bi[c * 64 + na + 1] + bh[c * 64 + na + 1];
  }

  // prefetch in0 for step 1 (layer0: emb gather t=0)
  float4 pf0, pf1, pf2, pf3;
  if (layer == 0) {
    int rid = x[(bg * 16 + r_st) * SS + 0];
    const float4* ep = (const float4*)(emb + (size_t)rid * 512 + ch * 16);
    pf0 = ep[0]; pf1 = ep[1]; pf2 = ep[2]; pf3 = ep[3];
  }

  for (int s = 1; s <= SS; ++s) {
    const u32 exp_h = (u32)((s - 1) & 7);

    // ============ phase 1: in0 path (h-independent) ============
    if (layer == 0) {
      // stage emb from prefetched f32 (swizzled s_in0)
      i32x4 v0, v1;
      v0[0] = pack2(f2bf(pf0.x), f2bf(pf0.y));
      v0[1] = pack2(f2bf(pf0.z), f2bf(pf0.w));
      v0[2] = pack2(f2bf(pf1.x), f2bf(pf1.y));
      v0[3] = pack2(f2bf(pf1.z), f2bf(pf1.w));
      v1[0] = pack2(f2bf(pf2.x), f2bf(pf2.y));
      v1[1] = pack2(f2bf(pf2.z), f2bf(pf2.w));
      v1[2] = pack2(f2bf(pf3.x), f2bf(pf3.y));
      v1[3] = pack2(f2bf(pf3.z), f2bf(pf3.w));
      *(i32x4*)(s_in0 + r_st * 512 + (((2 * ch) ^ (r_st & 7)) << 3)) = v0;
      *(i32x4*)(s_in0 + r_st * 512 + (((2 * ch + 1) ^ (r_st & 7)) << 3)) = v1;
      // issue emb prefetch for s+1 (survives lgkm-only barrier undrained)
      if (s < SS) {
        int rid = x[(bg * 16 + r_st) * SS + s];
        const float4* ep = (const float4*)(emb + (size_t)rid * 512 + ch * 16);
        pf0 = ep[0]; pf1 = ep[1]; pf2 = ep[2]; pf3 = ep[3];
      }
    } else {
      // layer1: poll in0[s] = out0[s] (self-contained spin, R8 shape)
      i32x4 i0 = {0, 0, 0, 0}, i1 = {0, 0, 0, 0}, i2 = {0, 0, 0, 0},
            i3 = {0, 0, 0, 0};
      const u32 exp_i = (u32)(s & 7);
      const u32* pi =
          hsl + (((size_t)(s & 3)) * 64 + bg * 16 + r_st) * 512 + ch * 16;
      while (true) {
        UC_LOAD4(i0, pi);
        UC_LOAD4(i1, pi + 4);
        UC_LOAD4(i2, pi + 8);
        UC_LOAD4(i3, pi + 12);
        asm volatile("s_waitcnt vmcnt(0)"
                     : "+v"(i0), "+v"(i1), "+v"(i2), "+v"(i3)::"memory");
        bool ok = tag4(i0, exp_i) && tag4(i1, exp_i) && tag4(i2, exp_i) &&
                  tag4(i3, exp_i);
        if (__all(ok)) break;
      }
      i32x4 A0 = {(int)hipack(i0[0], i0[1]), (int)hipack(i0[2], i0[3]),
                  (int)hipack(i1[0], i1[1]), (int)hipack(i1[2], i1[3])};
      i32x4 A1 = {(int)hipack(i2[0], i2[1]), (int)hipack(i2[2], i2[3]),
                  (int)hipack(i3[0], i3[1]), (int)hipack(i3[2], i3[3])};
      *(i32x4*)(s_in0 + r_st * 512 + (((2 * ch) ^ (r_st & 7)) << 3)) = A0;
      *(i32x4*)(s_in0 + r_st * 512 + (((2 * ch + 1) ^ (r_st & 7)) << 3)) = A1;
    }
    BAR_LDS();  // B1: s_in0 staged (LDS-only; vmem stays in flight)

    // ---- in0 MFMAs (h-independent; hide under producer publish) ----
    f32x4 acc0 = {0.f, 0.f, 0.f, 0.f};
    f32x4 acc1 = {0.f, 0.f, 0.f, 0.f};
    {
      const int r16 = lane & 15, kg = lane >> 4;
#pragma unroll
      for (int kt = 0; kt < 4; ++kt) {
        int k8 = kq * 16 + kt * 4 + kg;
        bf16x8 ain = __builtin_bit_cast(
            bf16x8, *(const i32x4*)(s_in0 + r16 * 512 + ((k8 ^ (r16 & 7)) << 3)));
        acc0 = __builtin_amdgcn_mfma_f32_16x16x32_bf16(ain, wih[0][kt], acc0, 0, 0, 0);
        acc1 = __builtin_amdgcn_mfma_f32_16x16x32_bf16(ain, wih[1][kt], acc1, 0, 0, 0);
      }
    }

    // ============ phase 3: per-wave H quarter (no barrier) ============
    if (s > 1) {
      // this wave polls its OWN quarter kq: rows {lr, lr+8}, cols
      // kq*128 + lch*16 .. +16 (16 u32 per row per lane)
      i32x4 w0 = {0,0,0,0}, w1 = {0,0,0,0}, w2 = {0,0,0,0}, w3 = {0,0,0,0};
      i32x4 w4 = {0,0,0,0}, w5 = {0,0,0,0}, w6 = {0,0,0,0}, w7 = {0,0,0,0};
      const u32* pq = hsl +
          (((size_t)layer * 4 + ((s - 1) & 3)) * 64 + bg * 16) * 512 + kq * 128;
      const u32* pA = pq + lr * 512 + lch * 16;
      const u32* pB = pA + 8 * 512;
      const bool bp_wave = (layer == 0) && (wid == 0) && (s > 4);
      const u32 exp_bp = (u32)((s - 4) & 7);
      const u32* pbp = hsl + ((size_t)(4 + ((s - 4) & 3)) * 64 + bg * 16) * 512 +
                       (lane < 8 ? lane * 64 : 0);
      while (true) {
        u32 bw = 0;
        UC_LOAD4(w0, pA);
        UC_LOAD4(w1, pA + 4);
        UC_LOAD4(w2, pA + 8);
        UC_LOAD4(w3, pA + 12);
        UC_LOAD4(w4, pB);
        UC_LOAD4(w5, pB + 4);
        UC_LOAD4(w6, pB + 8);
        UC_LOAD4(w7, pB + 12);
        if (bp_wave) UC_LOAD1(bw, pbp);
        asm volatile("s_waitcnt vmcnt(0)"
                     : "+v"(w0), "+v"(w1), "+v"(w2), "+v"(w3), "+v"(w4),
                       "+v"(w5), "+v"(w6), "+v"(w7), "+v"(bw)::"memory");
        bool ok = tag4(w0, exp_h) && tag4(w1, exp_h) && tag4(w2, exp_h) &&
                  tag4(w3, exp_h) && tag4(w4, exp_h) && tag4(w5, exp_h) &&
                  tag4(w6, exp_h) && tag4(w7, exp_h) &&
                  (!bp_wave || lane >= 8 || ((bw & 7u) == exp_bp));
        if (__all(ok)) break;
      }
      // stage quarter into pair-shared region (benign identical-value
      // race with pair partner). Chunks c0=lch*2, c0+1; rows lr, lr+8.
      {
        const int c0 = lch * 2;
        unsigned short* bh_ = s_Hq_hi + kq * 2048 + lr * 128;
        unsigned short* bl_ = s_Hq_lo + kq * 2048 + lr * 128;
        i32x4 T;
        T[0] = (int)hipack(w0[0], w0[1]); T[1] = (int)hipack(w0[2], w0[3]);
        T[2] = (int)hipack(w1[0], w1[1]); T[3] = (int)hipack(w1[2], w1[3]);
        *(i32x4*)(bh_ + (((c0 + 0) ^ (lr & 7)) << 3)) = T;
        T[0] = (int)hipack(w2[0], w2[1]); T[1] = (int)hipack(w2[2], w2[3]);
        T[2] = (int)hipack(w3[0], w3[1]); T[3] = (int)hipack(w3[2], w3[3]);
        *(i32x4*)(bh_ + (((c0 + 1) ^ (lr & 7)) << 3)) = T;
        T[0] = (int)lopack(w0[0], w0[1]); T[1] = (int)lopack(w0[2], w0[3]);
        T[2] = (int)lopack(w1[0], w1[1]); T[3] = (int)lopack(w1[2], w1[3]);
        *(i32x4*)(bl_ + (((c0 + 0) ^ (lr & 7)) << 3)) = T;
        T[0] = (int)lopack(w2[0], w2[1]); T[1] = (int)lopack(w2[2], w2[3]);
        T[2] = (int)lopack(w3[0], w3[1]); T[3] = (int)lopack(w3[2], w3[3]);
        *(i32x4*)(bl_ + (((c0 + 1) ^ (lr & 7)) << 3)) = T;
        unsigned short* bh2 = bh_ + 8 * 128;
        unsigned short* bl2 = bl_ + 8 * 128;
        T[0] = (int)hipack(w4[0], w4[1]); T[1] = (int)hipack(w4[2], w4[3]);
        T[2] = (int)hipack(w5[0], w5[1]); T[3] = (int)hipack(w5[2], w5[3]);
        *(i32x4*)(bh2 + (((c0 + 0) ^ (lr & 7)) << 3)) = T;
        T[0] = (int)hipack(w6[0], w6[1]); T[1] = (int)hipack(w6[2], w6[3]);
        T[2] = (int)hipack(w7[0], w7[1]); T[3] = (int)hipack(w7[2], w7[3]);
        *(i32x4*)(bh2 + (((c0 + 1) ^ (lr & 7)) << 3)) = T;
        T[0] = (int)lopack(w4[0], w4[1]); T[1] = (int)lopack(w4[2], w4[3]);
        T[2] = (int)lopack(w5[0], w5[1]); T[3] = (int)lopack(w5[2], w5[3]);
        *(i32x4*)(bl2 + (((c0 + 0) ^ (lr & 7)) << 3)) = T;
        T[0] = (int)lopack(w6[0], w6[1]); T[1] = (int)lopack(w6[2], w6[3]);
        T[2] = (int)lopack(w7[0], w7[1]); T[3] = (int)lopack(w7[2], w7[3]);
        *(i32x4*)(bl2 + (((c0 + 1) ^ (lr & 7)) << 3)) = T;
      }
      // H MFMAs straight away: this wave reads ONLY its quarter, which it
      // fully staged itself (compiler orders ds_read after ds_write).
      {
        const int r16 = lane & 15, kg = lane >> 4;
#pragma unroll
        for (int kt = 0; kt < 4; ++kt) {
          const int cidx = ((kt * 4 + kg) ^ (r16 & 7)) << 3;
          bf16x8 ahi = __builtin_bit_cast(
              bf16x8, *(const i32x4*)(s_Hq_hi + kq * 2048 + r16 * 128 + cidx));
          bf16x8 alo = __builtin_bit_cast(
              bf16x8, *(const i32x4*)(s_Hq_lo + kq * 2048 + r16 * 128 + cidx));
          acc0 = __builtin_amdgcn_mfma_f32_16x16x32_bf16(ahi, whhh[0][kt], acc0, 0, 0, 0);
          acc0 = __builtin_amdgcn_mfma_f32_16x16x32_bf16(ahi, whhl[0][kt], acc0, 0, 0, 0);
          acc0 = __builtin_amdgcn_mfma_f32_16x16x32_bf16(alo, whhh[0][kt], acc0, 0, 0, 0);
          acc1 = __builtin_amdgcn_mfma_f32_16x16x32_bf16(ahi, whhh[1][kt], acc1, 0, 0, 0);
          acc1 = __builtin_amdgcn_mfma_f32_16x16x32_bf16(ahi, whhl[1][kt], acc1, 0, 0, 0);
          acc1 = __builtin_amdgcn_mfma_f32_16x16x32_bf16(alo, whhh[1][kt], acc1, 0, 0, 0);
        }
      }
    }

    // ---- partial-sum write ----
    {
      const int r16 = lane & 15, kg = lane >> 4;
#pragma unroll
      for (int j = 0; j < 4; ++j) {
        int m = kg * 4 + j;
        int xr = (m >> 2) & 3;
        int n0i = nh * 32 + 0 * 16 + r16;
        int n1i = nh * 32 + 1 * 16 + r16;
        s_part[kq * 1024 + m * 64 + (n0i ^ (xr << 4))] = acc0[j];
        s_part[kq * 1024 + m * 64 + (n1i ^ (xr << 4))] = acc1[j];
      }
    }
    BAR_LDS();  // B3: s_part staged (only block-wide join on the h path)

    // ---- finals: reduce, bias, fast-tanh, pack word (hi|lo|tag), publish ----
    {
      int m = tid >> 5, na = (tid & 31) * 2;
      int xr = (m >> 2) & 3;
      float v0 = biasv0, v1 = biasv1;
#pragma unroll
      for (int q2 = 0; q2 < 4; ++q2) {
        const float2* sp =
            (const float2*)(s_part + q2 * 1024 + m * 64 + (na ^ (xr << 4)));
        float2 t = *sp;
        v0 += t.x;
        v1 += t.y;
      }
      v0 = fast_tanh(v0);
      v1 = fast_tanh(v1);
      unsigned short a0 = f2bf(v0), a1 = f2bf(v1);
      unsigned short b0 = f2bf(v0 - bf2f(a0)), b1 = f2bf(v1 - bf2f(a1));
      u32 tag = (u32)(s & 7);
      u32x2 wv;
      wv[0] = ((u32)a0 << 16) | ((u32)b0 & 0xFFF8u) | tag;
      wv[1] = ((u32)a1 << 16) | ((u32)b1 & 0xFFF8u) | tag;
      u32* dst = hsl + (((size_t)layer * 4 + (s & 3)) * 64 + bg * 16 + m) * 512 +
                 c * 64 + na;
      UC_STORE2(dst, wv);
    }
    // no drain, no flag: consumers detect via embedded tags.
    // s_Hq reuse next step is safe: writes for step s+1 happen after this
    // step's B3 on every wave (and only the owning pair touches a region).
  }
}

__global__ void k_fc(const u32* __restrict__ h1w, const float* __restrict__ fcW,
                     const float* __restrict__ fcb, float* __restrict__ out) {
  int i = threadIdx.x;  // 512 = 64 batch x 8 classes
  int b = i >> 3, cc = i & 7;
  float acc = fcb[cc];
  const u32* ph = h1w + b * 512;
  const float* pw = fcW + cc * 512;
  for (int k = 0; k < 512; k += 4) {
    int4 w4 = *(const int4*)(ph + k);
    float4 wv = *(const float4*)(pw + k);
    acc += (bf2f((unsigned short)((u32)w4.x >> 16)) +
            bf2f((unsigned short)((u32)w4.x & 0xFFF8u))) * wv.x;
    acc += (bf2f((unsigned short)((u32)w4.y >> 16)) +
            bf2f((unsigned short)((u32)w4.y & 0xFFF8u))) * wv.y;
    acc += (bf2f((unsigned short)((u32)w4.z >> 16)) +
            bf2f((unsigned short)((u32)w4.z & 0xFFF8u))) * wv.z;
    acc += (bf2f((unsigned short)((u32)w4.w >> 16)) +
            bf2f((unsigned short)((u32)w4.w & 0xFFF8u))) * wv.w;
  }
  out[b * 8 + cc] = acc;
}

extern "C" void kernel_launch(void* const* d_in, const int* in_sizes, int n_in,
                              void* d_out, int out_size, void* d_ws, size_t ws_size,
                              hipStream_t stream) {
  const int* x = (const int*)d_in[0];
  const float* emb = (const float*)d_in[1];
  const float* Wih0 = (const float*)d_in[2];
  const float* Whh0 = (const float*)d_in[3];
  const float* bih0 = (const float*)d_in[4];
  const float* bhh0 = (const float*)d_in[5];
  const float* Wih1 = (const float*)d_in[6];
  const float* Whh1 = (const float*)d_in[7];
  const float* bih1 = (const float*)d_in[8];
  const float* bhh1 = (const float*)d_in[9];
  const float* fcW = (const float*)d_in[10];
  const float* fcb = (const float*)d_in[11];

  u32* hsl = (u32*)d_ws;  // 2 layers x 4 slots x 64 x 512 u32 = 1 MB

  hipMemsetAsync(hsl, 0, (size_t)2 * 4 * 64 * 512 * 4, stream);
  hipLaunchKernelGGL(k_rnn, dim3(64), dim3(512), 0, stream, x, emb, Wih0, Whh0,
                     bih0, bhh0, Wih1, Whh1, bih1, bhh1, hsl);
  // final h1 = step 512 -> layer1 slot (512&3)==0
  hipLaunchKernelGGL(k_fc, dim3(1), dim3(512), 0, stream,
                     hsl + (size_t)4 * 64 * 512, fcW, fcb, (float*)d_out);
}

// Round 17
// 1764.940 us; speedup vs baseline: 1.3272x; 1.3272x over previous
//
#include <hip/hip_runtime.h>
#include <stdint.h>

// RNNTextClassifier: B=64, S=512, E=H=512, NCLS=8
// Round 20: revert to R18 (proven 1718us) + setprio on layer1's in0 spin.
// R19 post-mortem: per-wave-quarter H path re-serialized layer1's two
// MALL RTs (in0 then h) — the exact structure R15 removed for -15% —
// and tripled LDS conflicts. INVARIANT going forward: A/B concurrent
// polls must be preserved.
// R18 recap: A waves 0-3 = in0 path (layer0: stage emb + prefetch + bp
// spin on idle lanes; layer1: fused in0 poll+stage), B waves 4-7 =
// h[s-1] poll+stage with s_setprio(1). One __syncthreads joins, all 8
// waves MFMA (in0 + 3-term hi/lo H), s_part reduce, finals publish.
// R20 delta: layer1's A-group in0 spin also wrapped in s_setprio(1) —
// layer1's period is max(in0 RT, h RT); both spins are critical (T5).
// Protocol: ring slot=s&3, tag=s&7 in lo-word mantissa LSBs, bp at s-4,
// UC sc0 sc1 device-scope, launch_bounds(512,1).
// ws: hsl 1MB at offset 0 (memset to 0 each launch).

#define BB 64
#define SS 512
#define HH 512

typedef short bf16x8 __attribute__((ext_vector_type(8)));
typedef float f32x4 __attribute__((ext_vector_type(4)));
typedef int i32x4 __attribute__((ext_vector_type(4)));
typedef unsigned int u32;
typedef u32 u32x2 __attribute__((ext_vector_type(2)));

__device__ __forceinline__ unsigned short f2bf(float f) {
  uint32_t u = __builtin_bit_cast(uint32_t, f);
  u += 0x7FFFu + ((u >> 16) & 1u);
  return (unsigned short)(u >> 16);
}
__device__ __forceinline__ float bf2f(unsigned short h) {
  uint32_t u = ((uint32_t)h) << 16;
  return __builtin_bit_cast(float, u);
}
__device__ __forceinline__ int pack2(unsigned short a, unsigned short b) {
  return (int)(unsigned int)a | ((int)(unsigned int)b << 16);
}
__device__ __forceinline__ u32 hipack(u32 a, u32 b) {
  return (a >> 16) | (b & 0xFFFF0000u);
}
__device__ __forceinline__ u32 lopack(u32 a, u32 b) {
  return (a & 0xFFF8u) | ((b & 0xFFF8u) << 16);
}
__device__ __forceinline__ bool tag4(i32x4 v, u32 t) {
  u32 m = (((u32)v[0] ^ t) | ((u32)v[1] ^ t) | ((u32)v[2] ^ t) | ((u32)v[3] ^ t)) & 7u;
  return m == 0u;
}
__device__ __forceinline__ float fast_tanh(float v) {
  float a = __builtin_fabsf(v);
  float e = __expf(-2.0f * a);
  float t = (1.0f - e) / (1.0f + e);
  return __builtin_copysignf(t, v);
}

#define UC_LOAD4(dst, ptr) \
  asm volatile("global_load_dwordx4 %0, %1, off sc0 sc1" : "=v"(dst) : "v"(ptr))
#define UC_LOAD1(dst, ptr) \
  asm volatile("global_load_dword %0, %1, off sc0 sc1" : "=v"(dst) : "v"(ptr))
#define UC_STORE2(ptr, v) \
  asm volatile("global_store_dwordx2 %0, %1, off sc0 sc1" ::"v"(ptr), "v"(v) : "memory")

// issue one 8x dwordx4 batch over the lane's 4 chunks (cols 8gch + 128q)
#define ISSUE8(a0, a1, a2, a3, a4, a5, a6, a7, base)  \
  do {                                                \
    UC_LOAD4(a0, (base) + 8 * gch + 0);               \
    UC_LOAD4(a1, (base) + 8 * gch + 4);               \
    UC_LOAD4(a2, (base) + 8 * gch + 128);             \
    UC_LOAD4(a3, (base) + 8 * gch + 132);             \
    UC_LOAD4(a4, (base) + 8 * gch + 256);             \
    UC_LOAD4(a5, (base) + 8 * gch + 260);             \
    UC_LOAD4(a6, (base) + 8 * gch + 384);             \
    UC_LOAD4(a7, (base) + 8 * gch + 388);             \
  } while (0)

#define TAGOK8(a0, a1, a2, a3, a4, a5, a6, a7, t)                         \
  (tag4(a0, t) && tag4(a1, t) && tag4(a2, t) && tag4(a3, t) &&            \
   tag4(a4, t) && tag4(a5, t) && tag4(a6, t) && tag4(a7, t))

// stage hi halves into swizzled s_in0 (chunks gch+16j)
#define STAGE_IN0(w0, w1, w2, w3, w4, w5, w6, w7)                          \
  do {                                                                     \
    i32x4 A;                                                               \
    A[0] = (int)hipack(w0[0], w0[1]); A[1] = (int)hipack(w0[2], w0[3]);    \
    A[2] = (int)hipack(w1[0], w1[1]); A[3] = (int)hipack(w1[2], w1[3]);    \
    *(i32x4*)(s_in0 + gr * 512 + (((gch + 0) ^ (gr & 7)) << 3)) = A;       \
    A[0] = (int)hipack(w2[0], w2[1]); A[1] = (int)hipack(w2[2], w2[3]);    \
    A[2] = (int)hipack(w3[0], w3[1]); A[3] = (int)hipack(w3[2], w3[3]);    \
    *(i32x4*)(s_in0 + gr * 512 + (((gch + 16) ^ (gr & 7)) << 3)) = A;      \
    A[0] = (int)hipack(w4[0], w4[1]); A[1] = (int)hipack(w4[2], w4[3]);    \
    A[2] = (int)hipack(w5[0], w5[1]); A[3] = (int)hipack(w5[2], w5[3]);    \
    *(i32x4*)(s_in0 + gr * 512 + (((gch + 32) ^ (gr & 7)) << 3)) = A;      \
    A[0] = (int)hipack(w6[0], w6[1]); A[1] = (int)hipack(w6[2], w6[3]);    \
    A[2] = (int)hipack(w7[0], w7[1]); A[3] = (int)hipack(w7[2], w7[3]);    \
    *(i32x4*)(s_in0 + gr * 512 + (((gch + 48) ^ (gr & 7)) << 3)) = A;      \
  } while (0)

// stage H hi/lo into swizzled s_Hhi/s_Hlo (chunks gch+16j)
#define STAGE_H(w0, w1, w2, w3, w4, w5, w6, w7)                            \
  do {                                                                     \
    i32x4 A, B;                                                            \
    A[0] = (int)hipack(w0[0], w0[1]); A[1] = (int)hipack(w0[2], w0[3]);    \
    A[2] = (int)hipack(w1[0], w1[1]); A[3] = (int)hipack(w1[2], w1[3]);    \
    B[0] = (int)lopack(w0[0], w0[1]); B[1] = (int)lopack(w0[2], w0[3]);    \
    B[2] = (int)lopack(w1[0], w1[1]); B[3] = (int)lopack(w1[2], w1[3]);    \
    *(i32x4*)(s_Hhi + gr * 512 + (((gch + 0) ^ (gr & 7)) << 3)) = A;       \
    *(i32x4*)(s_Hlo + gr * 512 + (((gch + 0) ^ (gr & 7)) << 3)) = B;       \
    A[0] = (int)hipack(w2[0], w2[1]); A[1] = (int)hipack(w2[2], w2[3]);    \
    A[2] = (int)hipack(w3[0], w3[1]); A[3] = (int)hipack(w3[2], w3[3]);    \
    B[0] = (int)lopack(w2[0], w2[1]); B[1] = (int)lopack(w2[2], w2[3]);    \
    B[2] = (int)lopack(w3[0], w3[1]); B[3] = (int)lopack(w3[2], w3[3]);    \
    *(i32x4*)(s_Hhi + gr * 512 + (((gch + 16) ^ (gr & 7)) << 3)) = A;      \
    *(i32x4*)(s_Hlo + gr * 512 + (((gch + 16) ^ (gr & 7)) << 3)) = B;      \
    A[0] = (int)hipack(w4[0], w4[1]); A[1] = (int)hipack(w4[2], w4[3]);    \
    A[2] = (int)hipack(w5[0], w5[1]); A[3] = (int)hipack(w5[2], w5[3]);    \
    B[0] = (int)lopack(w4[0], w4[1]); B[1] = (int)lopack(w4[2], w4[3]);    \
    B[2] = (int)lopack(w5[0], w5[1]); B[3] = (int)lopack(w5[2], w5[3]);    \
    *(i32x4*)(s_Hhi + gr * 512 + (((gch + 32) ^ (gr & 7)) << 3)) = A;      \
    *(i32x4*)(s_Hlo + gr * 512 + (((gch + 32) ^ (gr & 7)) << 3)) = B;      \
    A[0] = (int)hipack(w6[0], w6[1]); A[1] = (int)hipack(w6[2], w6[3]);    \
    A[2] = (int)hipack(w7[0], w7[1]); A[3] = (int)hipack(w7[2], w7[3]);    \
    B[0] = (int)lopack(w6[0], w6[1]); B[1] = (int)lopack(w6[2], w6[3]);    \
    B[2] = (int)lopack(w7[0], w7[1]); B[3] = (int)lopack(w7[2], w7[3]);    \
    *(i32x4*)(s_Hhi + gr * 512 + (((gch + 48) ^ (gr & 7)) << 3)) = A;      \
    *(i32x4*)(s_Hlo + gr * 512 + (((gch + 48) ^ (gr & 7)) << 3)) = B;      \
  } while (0)

__global__ __launch_bounds__(512, 1) void k_rnn(
    const int* __restrict__ x, const float* __restrict__ emb,
    const float* __restrict__ Wih0, const float* __restrict__ Whh0,
    const float* __restrict__ bih0, const float* __restrict__ bhh0,
    const float* __restrict__ Wih1, const float* __restrict__ Whh1,
    const float* __restrict__ bih1, const float* __restrict__ bhh1,
    u32* __restrict__ hsl) {
  const int tid = threadIdx.x;
  const int bid = blockIdx.x;
  const int layer = bid >> 5;  // 0 or 1
  const int lb = bid & 31;
  const int bg = lb >> 3;  // batch group (16 rows)
  const int c = lb & 7;    // hidden slice (64 dims)
  const int wid = tid >> 6;
  const int lane = tid & 63;
  const int kq = wid >> 1;  // K-quarter (0..3)
  const int nh = wid & 1;   // N-half (32 cols)
  // staging-group index: A = waves 0..3, B = waves 4..7
  const int gt = tid & 255;
  const int gr = gt >> 4;   // row 0..15
  const int gch = gt & 15;  // chunk-base 0..15 (chunks gch+16j, j=0..3)

  __shared__ __align__(16) unsigned short s_in0[16 * 512];
  __shared__ __align__(16) unsigned short s_Hhi[16 * 512];
  __shared__ __align__(16) unsigned short s_Hlo[16 * 512];
  __shared__ __align__(16) float s_part[4 * 16 * 64];

  const float* Wih = layer ? Wih1 : Wih0;
  const float* Whh = layer ? Whh1 : Whh0;
  const float* bi = layer ? bih1 : bih0;
  const float* bh = layer ? bhh1 : bhh0;

  // ---- one-time: W fragments into VGPRs (mapping unchanged from R8) ----
  bf16x8 wih[2][4], whhh[2][4], whhl[2][4];
  {
    const int r16 = lane & 15, kg = lane >> 4;
#pragma unroll
    for (int nt = 0; nt < 2; ++nt) {
#pragma unroll
      for (int kt = 0; kt < 4; ++kt) {
        int row = c * 64 + nh * 32 + nt * 16 + r16;
        int k0 = kq * 128 + kt * 32 + kg * 8;
        const float* p = Wih + row * 512 + k0;
        bf16x8 v;
#pragma unroll
        for (int j = 0; j < 8; ++j) v[j] = (short)f2bf(p[j]);
        wih[nt][kt] = v;
        const float* q = Whh + row * 512 + k0;
        bf16x8 vh, vl;
#pragma unroll
        for (int j = 0; j < 8; ++j) {
          float f = q[j];
          unsigned short h = f2bf(f);
          vh[j] = (short)h;
          vl[j] = (short)f2bf(f - bf2f(h));
        }
        whhh[nt][kt] = vh;
        whhl[nt][kt] = vl;
      }
    }
  }
  float biasv0, biasv1;
  {
    int na = (tid & 31) * 2;
    biasv0 = bi[c * 64 + na] + bh[c * 64 + na];
    biasv1 = bi[c * 64 + na + 1] + bh[c * 64 + na + 1];
  }

  // A-group (layer0): emb prefetch for step 1 — 8 float4 per thread
  float4 pf0, pf1, pf2, pf3, pf4, pf5, pf6, pf7;
  if (layer == 0 && wid < 4) {
    int rid = x[(bg * 16 + gr) * SS + 0];
    const float4* ep = (const float4*)(emb + (size_t)rid * 512);
    pf0 = ep[2 * gch + 0];  pf1 = ep[2 * gch + 1];
    pf2 = ep[2 * gch + 32]; pf3 = ep[2 * gch + 33];
    pf4 = ep[2 * gch + 64]; pf5 = ep[2 * gch + 65];
    pf6 = ep[2 * gch + 96]; pf7 = ep[2 * gch + 97];
  }

  for (int s = 1; s <= SS; ++s) {
    const u32 exp_h = (u32)((s - 1) & 7);

    if (wid < 4) {
      // ================= A-group: in0 path =================
      if (layer == 0) {
        // stage emb (chunks gch+16j) from prefetch
        {
          i32x4 v;
          v[0] = pack2(f2bf(pf0.x), f2bf(pf0.y));
          v[1] = pack2(f2bf(pf0.z), f2bf(pf0.w));
          v[2] = pack2(f2bf(pf1.x), f2bf(pf1.y));
          v[3] = pack2(f2bf(pf1.z), f2bf(pf1.w));
          *(i32x4*)(s_in0 + gr * 512 + (((gch + 0) ^ (gr & 7)) << 3)) = v;
          v[0] = pack2(f2bf(pf2.x), f2bf(pf2.y));
          v[1] = pack2(f2bf(pf2.z), f2bf(pf2.w));
          v[2] = pack2(f2bf(pf3.x), f2bf(pf3.y));
          v[3] = pack2(f2bf(pf3.z), f2bf(pf3.w));
          *(i32x4*)(s_in0 + gr * 512 + (((gch + 16) ^ (gr & 7)) << 3)) = v;
          v[0] = pack2(f2bf(pf4.x), f2bf(pf4.y));
          v[1] = pack2(f2bf(pf4.z), f2bf(pf4.w));
          v[2] = pack2(f2bf(pf5.x), f2bf(pf5.y));
          v[3] = pack2(f2bf(pf5.z), f2bf(pf5.w));
          *(i32x4*)(s_in0 + gr * 512 + (((gch + 32) ^ (gr & 7)) << 3)) = v;
          v[0] = pack2(f2bf(pf6.x), f2bf(pf6.y));
          v[1] = pack2(f2bf(pf6.z), f2bf(pf6.w));
          v[2] = pack2(f2bf(pf7.x), f2bf(pf7.y));
          v[3] = pack2(f2bf(pf7.z), f2bf(pf7.w));
          *(i32x4*)(s_in0 + gr * 512 + (((gch + 48) ^ (gr & 7)) << 3)) = v;
        }
        // issue emb prefetch for s+1 (hides under barrier + MFMA + B-poll)
        if (s < SS) {
          int rid = x[(bg * 16 + gr) * SS + s];
          const float4* ep = (const float4*)(emb + (size_t)rid * 512);
          pf0 = ep[2 * gch + 0];  pf1 = ep[2 * gch + 1];
          pf2 = ep[2 * gch + 32]; pf3 = ep[2 * gch + 33];
          pf4 = ep[2 * gch + 64]; pf5 = ep[2 * gch + 65];
          pf6 = ep[2 * gch + 96]; pf7 = ep[2 * gch + 97];
        }
        // bp check on idle A-waves: layer1 must have consumed slot s-4
        if (s > 4) {
          const u32 exp_bp = (u32)((s - 4) & 7);
          const u32* pbp = hsl + ((size_t)(4 + ((s - 4) & 3)) * 64 + bg * 16) * 512 +
                           (gt < 8 ? gt * 64 : 0);
          u32 bw = 0;
          while (true) {
            UC_LOAD1(bw, pbp);
            asm volatile("s_waitcnt vmcnt(0)" : "+v"(bw)::"memory");
            if (__all(gt >= 8 || ((bw & 7u) == exp_bp))) break;
          }
        }
      } else {
        // layer1: poll in0[s] = out0[s] (fused detect+transfer spin)
        __builtin_amdgcn_s_setprio(1);
        i32x4 w0 = {0,0,0,0}, w1 = {0,0,0,0}, w2 = {0,0,0,0}, w3 = {0,0,0,0};
        i32x4 w4 = {0,0,0,0}, w5 = {0,0,0,0}, w6 = {0,0,0,0}, w7 = {0,0,0,0};
        const u32 exp_i = (u32)(s & 7);
        const u32* pib =
            hsl + (((size_t)(s & 3)) * 64 + bg * 16 + gr) * 512;
        while (true) {
          ISSUE8(w0, w1, w2, w3, w4, w5, w6, w7, pib);
          asm volatile("s_waitcnt vmcnt(0)"
                       : "+v"(w0), "+v"(w1), "+v"(w2), "+v"(w3), "+v"(w4),
                         "+v"(w5), "+v"(w6), "+v"(w7)::"memory");
          if (__all(TAGOK8(w0, w1, w2, w3, w4, w5, w6, w7, exp_i))) break;
        }
        STAGE_IN0(w0, w1, w2, w3, w4, w5, w6, w7);
        __builtin_amdgcn_s_setprio(0);
      }
    } else {
      // ================= B-group: h[s-1] path (pure h spin) =============
      if (s > 1) {
        __builtin_amdgcn_s_setprio(1);
        i32x4 w0 = {0,0,0,0}, w1 = {0,0,0,0}, w2 = {0,0,0,0}, w3 = {0,0,0,0};
        i32x4 w4 = {0,0,0,0}, w5 = {0,0,0,0}, w6 = {0,0,0,0}, w7 = {0,0,0,0};
        const u32* phb = hsl +
            (((size_t)layer * 4 + ((s - 1) & 3)) * 64 + bg * 16 + gr) * 512;
        while (true) {
          ISSUE8(w0, w1, w2, w3, w4, w5, w6, w7, phb);
          asm volatile("s_waitcnt vmcnt(0)"
                       : "+v"(w0), "+v"(w1), "+v"(w2), "+v"(w3), "+v"(w4),
                         "+v"(w5), "+v"(w6), "+v"(w7)::"memory");
          if (__all(TAGOK8(w0, w1, w2, w3, w4, w5, w6, w7, exp_h))) break;
        }
        STAGE_H(w0, w1, w2, w3, w4, w5, w6, w7);
        __builtin_amdgcn_s_setprio(0);
      }
    }
    __syncthreads();  // B1: s_in0 + s_H staged (A and B joined; bp enforced)

    // ---- full MFMA phase: all 8 waves, roles unchanged ----
    f32x4 acc0 = {0.f, 0.f, 0.f, 0.f};
    f32x4 acc1 = {0.f, 0.f, 0.f, 0.f};
    {
      const int r16 = lane & 15, kg = lane >> 4;
#pragma unroll
      for (int kt = 0; kt < 4; ++kt) {
        int k8 = kq * 16 + kt * 4 + kg;
        bf16x8 ain = __builtin_bit_cast(
            bf16x8, *(const i32x4*)(s_in0 + r16 * 512 + ((k8 ^ (r16 & 7)) << 3)));
        acc0 = __builtin_amdgcn_mfma_f32_16x16x32_bf16(ain, wih[0][kt], acc0, 0, 0, 0);
        acc1 = __builtin_amdgcn_mfma_f32_16x16x32_bf16(ain, wih[1][kt], acc1, 0, 0, 0);
      }
      if (s > 1) {
#pragma unroll
        for (int kt = 0; kt < 4; ++kt) {
          int k8 = kq * 16 + kt * 4 + kg;
          bf16x8 ahi = __builtin_bit_cast(
              bf16x8, *(const i32x4*)(s_Hhi + r16 * 512 + ((k8 ^ (r16 & 7)) << 3)));
          bf16x8 alo = __builtin_bit_cast(
              bf16x8, *(const i32x4*)(s_Hlo + r16 * 512 + ((k8 ^ (r16 & 7)) << 3)));
          acc0 = __builtin_amdgcn_mfma_f32_16x16x32_bf16(ahi, whhh[0][kt], acc0, 0, 0, 0);
          acc0 = __builtin_amdgcn_mfma_f32_16x16x32_bf16(ahi, whhl[0][kt], acc0, 0, 0, 0);
          acc0 = __builtin_amdgcn_mfma_f32_16x16x32_bf16(alo, whhh[0][kt], acc0, 0, 0, 0);
          acc1 = __builtin_amdgcn_mfma_f32_16x16x32_bf16(ahi, whhh[1][kt], acc1, 0, 0, 0);
          acc1 = __builtin_amdgcn_mfma_f32_16x16x32_bf16(ahi, whhl[1][kt], acc1, 0, 0, 0);
          acc1 = __builtin_amdgcn_mfma_f32_16x16x32_bf16(alo, whhh[1][kt], acc1, 0, 0, 0);
        }
      }
#pragma unroll
      for (int j = 0; j < 4; ++j) {
        int m = kg * 4 + j;
        int xr = (m >> 2) & 3;
        int n0i = nh * 32 + 0 * 16 + r16;
        int n1i = nh * 32 + 1 * 16 + r16;
        s_part[kq * 1024 + m * 64 + (n0i ^ (xr << 4))] = acc0[j];
        s_part[kq * 1024 + m * 64 + (n1i ^ (xr << 4))] = acc1[j];
      }
    }
    __syncthreads();  // B3

    // ---- finals: reduce, bias, fast-tanh, pack word (hi|lo|tag), publish ----
    {
      int m = tid >> 5, na = (tid & 31) * 2;
      int xr = (m >> 2) & 3;
      float v0 = biasv0, v1 = biasv1;
#pragma unroll
      for (int q2 = 0; q2 < 4; ++q2) {
        const float2* sp =
            (const float2*)(s_part + q2 * 1024 + m * 64 + (na ^ (xr << 4)));
        float2 t = *sp;
        v0 += t.x;
        v1 += t.y;
      }
      v0 = fast_tanh(v0);
      v1 = fast_tanh(v1);
      unsigned short a0 = f2bf(v0), a1 = f2bf(v1);
      unsigned short b0 = f2bf(v0 - bf2f(a0)), b1 = f2bf(v1 - bf2f(a1));
      u32 tag = (u32)(s & 7);
      u32x2 wv;
      wv[0] = ((u32)a0 << 16) | ((u32)b0 & 0xFFF8u) | tag;
      wv[1] = ((u32)a1 << 16) | ((u32)b1 & 0xFFF8u) | tag;
      u32* dst = hsl + (((size_t)layer * 4 + (s & 3)) * 64 + bg * 16 + m) * 512 +
                 c * 64 + na;
      UC_STORE2(dst, wv);
    }
    // no drain, no flag: consumers detect via embedded tags
  }
}

__global__ void k_fc(const u32* __restrict__ h1w, const float* __restrict__ fcW,
                     const float* __restrict__ fcb, float* __restrict__ out) {
  int i = threadIdx.x;  // 512 = 64 batch x 8 classes
  int b = i >> 3, cc = i & 7;
  float acc = fcb[cc];
  const u32* ph = h1w + b * 512;
  const float* pw = fcW + cc * 512;
  for (int k = 0; k < 512; k += 4) {
    int4 w4 = *(const int4*)(ph + k);
    float4 wv = *(const float4*)(pw + k);
    acc += (bf2f((unsigned short)((u32)w4.x >> 16)) +
            bf2f((unsigned short)((u32)w4.x & 0xFFF8u))) * wv.x;
    acc += (bf2f((unsigned short)((u32)w4.y >> 16)) +
            bf2f((unsigned short)((u32)w4.y & 0xFFF8u))) * wv.y;
    acc += (bf2f((unsigned short)((u32)w4.z >> 16)) +
            bf2f((unsigned short)((u32)w4.z & 0xFFF8u))) * wv.z;
    acc += (bf2f((unsigned short)((u32)w4.w >> 16)) +
            bf2f((unsigned short)((u32)w4.w & 0xFFF8u))) * wv.w;
  }
  out[b * 8 + cc] = acc;
}

extern "C" void kernel_launch(void* const* d_in, const int* in_sizes, int n_in,
                              void* d_out, int out_size, void* d_ws, size_t ws_size,
                              hipStream_t stream) {
  const int* x = (const int*)d_in[0];
  const float* emb = (const float*)d_in[1];
  const float* Wih0 = (const float*)d_in[2];
  const float* Whh0 = (const float*)d_in[3];
  const float* bih0 = (const float*)d_in[4];
  const float* bhh0 = (const float*)d_in[5];
  const float* Wih1 = (const float*)d_in[6];
  const float* Whh1 = (const float*)d_in[7];
  const float* bih1 = (const float*)d_in[8];
  const float* bhh1 = (const float*)d_in[9];
  const float* fcW = (const float*)d_in[10];
  const float* fcb = (const float*)d_in[11];

  u32* hsl = (u32*)d_ws;  // 2 layers x 4 slots x 64 x 512 u32 = 1 MB

  hipMemsetAsync(hsl, 0, (size_t)2 * 4 * 64 * 512 * 4, stream);
  hipLaunchKernelGGL(k_rnn, dim3(64), dim3(512), 0, stream, x, emb, Wih0, Whh0,
                     bih0, bhh0, Wih1, Whh1, bih1, bhh1, hsl);
  // final h1 = step 512 -> layer1 slot (512&3)==0
  hipLaunchKernelGGL(k_fc, dim3(1), dim3(512), 0, stream,
                     hsl + (size_t)4 * 64 * 512, fcW, fcb, (float*)d_out);
}

// Round 18
// 1734.885 us; speedup vs baseline: 1.3502x; 1.0173x over previous
//
#include <hip/hip_runtime.h>
#include <stdint.h>

// RNNTextClassifier: B=64, S=512, E=H=512, NCLS=8
// Round 21: byte-exact revert to R18 — the session's best (1718us).
// R20 isolated that extending s_setprio(1) to layer1's A in0-spin HURT
// (+46us): the A and B spins co-resident on a CU compete for issue
// slots; boosting both == boosting neither + toggle overhead. R18's
// asymmetric config (setprio ONLY on the B h-spin) is the optimum.
// Final structure (proven):
//  - A waves 0-3 = in0 path: layer0 stages emb from prefetch, issues
//    next prefetch, then runs the bp spin on idle lanes; layer1 runs the
//    fused in0 poll+stage (detect+transfer in one RT).
//  - B waves 4-7 = h[s-1] path: fused poll+stage, setprio(1)-wrapped.
//  - One __syncthreads joins A/B (the R15 invariant: the two MALL RTs
//    run CONCURRENTLY); all 8 waves MFMA (in0 + 3-term hi/lo H);
//    s_part cross-wave reduce; finals: bias+fast_tanh+pack+publish.
// Protocol: tagged-data ring slot=s&3, tag=s&7 in lo-word mantissa LSBs,
// bp at s-4, UC sc0 sc1 device-scope, launch_bounds(512,1).
// Session ledger: wins R6 fast_tanh, R8 reorder, R15 parallel polls,
// R18 bp-offload+setprio. Refuted: XCD-local sc0 sync (R4/R5), per-wave
// full-K (R9/R13), reg-direct poll (R10), barrier surgery (R11), merged
// poll/8-slot ring (R12), pipelined poll (R16), sentinel poll (R17),
// per-quarter H (R19), symmetric setprio (R20). Remaining 3.36us/step =
// cross-CU device-scope publish->MALL->detect RT x max(8 publishers):
// latency wall, not a memory (HBM 6.8%) or compute (MFMA 3.2%) roofline.
// ws: hsl 1MB at offset 0 (memset to 0 each launch).

#define BB 64
#define SS 512
#define HH 512

typedef short bf16x8 __attribute__((ext_vector_type(8)));
typedef float f32x4 __attribute__((ext_vector_type(4)));
typedef int i32x4 __attribute__((ext_vector_type(4)));
typedef unsigned int u32;
typedef u32 u32x2 __attribute__((ext_vector_type(2)));

__device__ __forceinline__ unsigned short f2bf(float f) {
  uint32_t u = __builtin_bit_cast(uint32_t, f);
  u += 0x7FFFu + ((u >> 16) & 1u);
  return (unsigned short)(u >> 16);
}
__device__ __forceinline__ float bf2f(unsigned short h) {
  uint32_t u = ((uint32_t)h) << 16;
  return __builtin_bit_cast(float, u);
}
__device__ __forceinline__ int pack2(unsigned short a, unsigned short b) {
  return (int)(unsigned int)a | ((int)(unsigned int)b << 16);
}
__device__ __forceinline__ u32 hipack(u32 a, u32 b) {
  return (a >> 16) | (b & 0xFFFF0000u);
}
__device__ __forceinline__ u32 lopack(u32 a, u32 b) {
  return (a & 0xFFF8u) | ((b & 0xFFF8u) << 16);
}
__device__ __forceinline__ bool tag4(i32x4 v, u32 t) {
  u32 m = (((u32)v[0] ^ t) | ((u32)v[1] ^ t) | ((u32)v[2] ^ t) | ((u32)v[3] ^ t)) & 7u;
  return m == 0u;
}
__device__ __forceinline__ float fast_tanh(float v) {
  float a = __builtin_fabsf(v);
  float e = __expf(-2.0f * a);
  float t = (1.0f - e) / (1.0f + e);
  return __builtin_copysignf(t, v);
}

#define UC_LOAD4(dst, ptr) \
  asm volatile("global_load_dwordx4 %0, %1, off sc0 sc1" : "=v"(dst) : "v"(ptr))
#define UC_LOAD1(dst, ptr) \
  asm volatile("global_load_dword %0, %1, off sc0 sc1" : "=v"(dst) : "v"(ptr))
#define UC_STORE2(ptr, v) \
  asm volatile("global_store_dwordx2 %0, %1, off sc0 sc1" ::"v"(ptr), "v"(v) : "memory")

// issue one 8x dwordx4 batch over the lane's 4 chunks (cols 8gch + 128q)
#define ISSUE8(a0, a1, a2, a3, a4, a5, a6, a7, base)  \
  do {                                                \
    UC_LOAD4(a0, (base) + 8 * gch + 0);               \
    UC_LOAD4(a1, (base) + 8 * gch + 4);               \
    UC_LOAD4(a2, (base) + 8 * gch + 128);             \
    UC_LOAD4(a3, (base) + 8 * gch + 132);             \
    UC_LOAD4(a4, (base) + 8 * gch + 256);             \
    UC_LOAD4(a5, (base) + 8 * gch + 260);             \
    UC_LOAD4(a6, (base) + 8 * gch + 384);             \
    UC_LOAD4(a7, (base) + 8 * gch + 388);             \
  } while (0)

#define TAGOK8(a0, a1, a2, a3, a4, a5, a6, a7, t)                         \
  (tag4(a0, t) && tag4(a1, t) && tag4(a2, t) && tag4(a3, t) &&            \
   tag4(a4, t) && tag4(a5, t) && tag4(a6, t) && tag4(a7, t))

// stage hi halves into swizzled s_in0 (chunks gch+16j)
#define STAGE_IN0(w0, w1, w2, w3, w4, w5, w6, w7)                          \
  do {                                                                     \
    i32x4 A;                                                               \
    A[0] = (int)hipack(w0[0], w0[1]); A[1] = (int)hipack(w0[2], w0[3]);    \
    A[2] = (int)hipack(w1[0], w1[1]); A[3] = (int)hipack(w1[2], w1[3]);    \
    *(i32x4*)(s_in0 + gr * 512 + (((gch + 0) ^ (gr & 7)) << 3)) = A;       \
    A[0] = (int)hipack(w2[0], w2[1]); A[1] = (int)hipack(w2[2], w2[3]);    \
    A[2] = (int)hipack(w3[0], w3[1]); A[3] = (int)hipack(w3[2], w3[3]);    \
    *(i32x4*)(s_in0 + gr * 512 + (((gch + 16) ^ (gr & 7)) << 3)) = A;      \
    A[0] = (int)hipack(w4[0], w4[1]); A[1] = (int)hipack(w4[2], w4[3]);    \
    A[2] = (int)hipack(w5[0], w5[1]); A[3] = (int)hipack(w5[2], w5[3]);    \
    *(i32x4*)(s_in0 + gr * 512 + (((gch + 32) ^ (gr & 7)) << 3)) = A;      \
    A[0] = (int)hipack(w6[0], w6[1]); A[1] = (int)hipack(w6[2], w6[3]);    \
    A[2] = (int)hipack(w7[0], w7[1]); A[3] = (int)hipack(w7[2], w7[3]);    \
    *(i32x4*)(s_in0 + gr * 512 + (((gch + 48) ^ (gr & 7)) << 3)) = A;      \
  } while (0)

// stage H hi/lo into swizzled s_Hhi/s_Hlo (chunks gch+16j)
#define STAGE_H(w0, w1, w2, w3, w4, w5, w6, w7)                            \
  do {                                                                     \
    i32x4 A, B;                                                            \
    A[0] = (int)hipack(w0[0], w0[1]); A[1] = (int)hipack(w0[2], w0[3]);    \
    A[2] = (int)hipack(w1[0], w1[1]); A[3] = (int)hipack(w1[2], w1[3]);    \
    B[0] = (int)lopack(w0[0], w0[1]); B[1] = (int)lopack(w0[2], w0[3]);    \
    B[2] = (int)lopack(w1[0], w1[1]); B[3] = (int)lopack(w1[2], w1[3]);    \
    *(i32x4*)(s_Hhi + gr * 512 + (((gch + 0) ^ (gr & 7)) << 3)) = A;       \
    *(i32x4*)(s_Hlo + gr * 512 + (((gch + 0) ^ (gr & 7)) << 3)) = B;       \
    A[0] = (int)hipack(w2[0], w2[1]); A[1] = (int)hipack(w2[2], w2[3]);    \
    A[2] = (int)hipack(w3[0], w3[1]); A[3] = (int)hipack(w3[2], w3[3]);    \
    B[0] = (int)lopack(w2[0], w2[1]); B[1] = (int)lopack(w2[2], w2[3]);    \
    B[2] = (int)lopack(w3[0], w3[1]); B[3] = (int)lopack(w3[2], w3[3]);    \
    *(i32x4*)(s_Hhi + gr * 512 + (((gch + 16) ^ (gr & 7)) << 3)) = A;      \
    *(i32x4*)(s_Hlo + gr * 512 + (((gch + 16) ^ (gr & 7)) << 3)) = B;      \
    A[0] = (int)hipack(w4[0], w4[1]); A[1] = (int)hipack(w4[2], w4[3]);    \
    A[2] = (int)hipack(w5[0], w5[1]); A[3] = (int)hipack(w5[2], w5[3]);    \
    B[0] = (int)lopack(w4[0], w4[1]); B[1] = (int)lopack(w4[2], w4[3]);    \
    B[2] = (int)lopack(w5[0], w5[1]); B[3] = (int)lopack(w5[2], w5[3]);    \
    *(i32x4*)(s_Hhi + gr * 512 + (((gch + 32) ^ (gr & 7)) << 3)) = A;      \
    *(i32x4*)(s_Hlo + gr * 512 + (((gch + 32) ^ (gr & 7)) << 3)) = B;      \
    A[0] = (int)hipack(w6[0], w6[1]); A[1] = (int)hipack(w6[2], w6[3]);    \
    A[2] = (int)hipack(w7[0], w7[1]); A[3] = (int)hipack(w7[2], w7[3]);    \
    B[0] = (int)lopack(w6[0], w6[1]); B[1] = (int)lopack(w6[2], w6[3]);    \
    B[2] = (int)lopack(w7[0], w7[1]); B[3] = (int)lopack(w7[2], w7[3]);    \
    *(i32x4*)(s_Hhi + gr * 512 + (((gch + 48) ^ (gr & 7)) << 3)) = A;      \
    *(i32x4*)(s_Hlo + gr * 512 + (((gch + 48) ^ (gr & 7)) << 3)) = B;      \
  } while (0)

__global__ __launch_bounds__(512, 1) void k_rnn(
    const int* __restrict__ x, const float* __restrict__ emb,
    const float* __restrict__ Wih0, const float* __restrict__ Whh0,
    const float* __restrict__ bih0, const float* __restrict__ bhh0,
    const float* __restrict__ Wih1, const float* __restrict__ Whh1,
    const float* __restrict__ bih1, const float* __restrict__ bhh1,
    u32* __restrict__ hsl) {
  const int tid = threadIdx.x;
  const int bid = blockIdx.x;
  const int layer = bid >> 5;  // 0 or 1
  const int lb = bid & 31;
  const int bg = lb >> 3;  // batch group (16 rows)
  const int c = lb & 7;    // hidden slice (64 dims)
  const int wid = tid >> 6;
  const int lane = tid & 63;
  const int kq = wid >> 1;  // K-quarter (0..3)
  const int nh = wid & 1;   // N-half (32 cols)
  // staging-group index: A = waves 0..3, B = waves 4..7
  const int gt = tid & 255;
  const int gr = gt >> 4;   // row 0..15
  const int gch = gt & 15;  // chunk-base 0..15 (chunks gch+16j, j=0..3)

  __shared__ __align__(16) unsigned short s_in0[16 * 512];
  __shared__ __align__(16) unsigned short s_Hhi[16 * 512];
  __shared__ __align__(16) unsigned short s_Hlo[16 * 512];
  __shared__ __align__(16) float s_part[4 * 16 * 64];

  const float* Wih = layer ? Wih1 : Wih0;
  const float* Whh = layer ? Whh1 : Whh0;
  const float* bi = layer ? bih1 : bih0;
  const float* bh = layer ? bhh1 : bhh0;

  // ---- one-time: W fragments into VGPRs (mapping unchanged from R8) ----
  bf16x8 wih[2][4], whhh[2][4], whhl[2][4];
  {
    const int r16 = lane & 15, kg = lane >> 4;
#pragma unroll
    for (int nt = 0; nt < 2; ++nt) {
#pragma unroll
      for (int kt = 0; kt < 4; ++kt) {
        int row = c * 64 + nh * 32 + nt * 16 + r16;
        int k0 = kq * 128 + kt * 32 + kg * 8;
        const float* p = Wih + row * 512 + k0;
        bf16x8 v;
#pragma unroll
        for (int j = 0; j < 8; ++j) v[j] = (short)f2bf(p[j]);
        wih[nt][kt] = v;
        const float* q = Whh + row * 512 + k0;
        bf16x8 vh, vl;
#pragma unroll
        for (int j = 0; j < 8; ++j) {
          float f = q[j];
          unsigned short h = f2bf(f);
          vh[j] = (short)h;
          vl[j] = (short)f2bf(f - bf2f(h));
        }
        whhh[nt][kt] = vh;
        whhl[nt][kt] = vl;
      }
    }
  }
  float biasv0, biasv1;
  {
    int na = (tid & 31) * 2;
    biasv0 = bi[c * 64 + na] + bh[c * 64 + na];
    biasv1 = bi[c * 64 + na + 1] + bh[c * 64 + na + 1];
  }

  // A-group (layer0): emb prefetch for step 1 — 8 float4 per thread
  float4 pf0, pf1, pf2, pf3, pf4, pf5, pf6, pf7;
  if (layer == 0 && wid < 4) {
    int rid = x[(bg * 16 + gr) * SS + 0];
    const float4* ep = (const float4*)(emb + (size_t)rid * 512);
    pf0 = ep[2 * gch + 0];  pf1 = ep[2 * gch + 1];
    pf2 = ep[2 * gch + 32]; pf3 = ep[2 * gch + 33];
    pf4 = ep[2 * gch + 64]; pf5 = ep[2 * gch + 65];
    pf6 = ep[2 * gch + 96]; pf7 = ep[2 * gch + 97];
  }

  for (int s = 1; s <= SS; ++s) {
    const u32 exp_h = (u32)((s - 1) & 7);

    if (wid < 4) {
      // ================= A-group: in0 path =================
      if (layer == 0) {
        // stage emb (chunks gch+16j) from prefetch
        {
          i32x4 v;
          v[0] = pack2(f2bf(pf0.x), f2bf(pf0.y));
          v[1] = pack2(f2bf(pf0.z), f2bf(pf0.w));
          v[2] = pack2(f2bf(pf1.x), f2bf(pf1.y));
          v[3] = pack2(f2bf(pf1.z), f2bf(pf1.w));
          *(i32x4*)(s_in0 + gr * 512 + (((gch + 0) ^ (gr & 7)) << 3)) = v;
          v[0] = pack2(f2bf(pf2.x), f2bf(pf2.y));
          v[1] = pack2(f2bf(pf2.z), f2bf(pf2.w));
          v[2] = pack2(f2bf(pf3.x), f2bf(pf3.y));
          v[3] = pack2(f2bf(pf3.z), f2bf(pf3.w));
          *(i32x4*)(s_in0 + gr * 512 + (((gch + 16) ^ (gr & 7)) << 3)) = v;
          v[0] = pack2(f2bf(pf4.x), f2bf(pf4.y));
          v[1] = pack2(f2bf(pf4.z), f2bf(pf4.w));
          v[2] = pack2(f2bf(pf5.x), f2bf(pf5.y));
          v[3] = pack2(f2bf(pf5.z), f2bf(pf5.w));
          *(i32x4*)(s_in0 + gr * 512 + (((gch + 32) ^ (gr & 7)) << 3)) = v;
          v[0] = pack2(f2bf(pf6.x), f2bf(pf6.y));
          v[1] = pack2(f2bf(pf6.z), f2bf(pf6.w));
          v[2] = pack2(f2bf(pf7.x), f2bf(pf7.y));
          v[3] = pack2(f2bf(pf7.z), f2bf(pf7.w));
          *(i32x4*)(s_in0 + gr * 512 + (((gch + 48) ^ (gr & 7)) << 3)) = v;
        }
        // issue emb prefetch for s+1 (hides under barrier + MFMA + B-poll)
        if (s < SS) {
          int rid = x[(bg * 16 + gr) * SS + s];
          const float4* ep = (const float4*)(emb + (size_t)rid * 512);
          pf0 = ep[2 * gch + 0];  pf1 = ep[2 * gch + 1];
          pf2 = ep[2 * gch + 32]; pf3 = ep[2 * gch + 33];
          pf4 = ep[2 * gch + 64]; pf5 = ep[2 * gch + 65];
          pf6 = ep[2 * gch + 96]; pf7 = ep[2 * gch + 97];
        }
        // bp check on idle A-waves: layer1 must have consumed slot s-4
        if (s > 4) {
          const u32 exp_bp = (u32)((s - 4) & 7);
          const u32* pbp = hsl + ((size_t)(4 + ((s - 4) & 3)) * 64 + bg * 16) * 512 +
                           (gt < 8 ? gt * 64 : 0);
          u32 bw = 0;
          while (true) {
            UC_LOAD1(bw, pbp);
            asm volatile("s_waitcnt vmcnt(0)" : "+v"(bw)::"memory");
            if (__all(gt >= 8 || ((bw & 7u) == exp_bp))) break;
          }
        }
      } else {
        // layer1: poll in0[s] = out0[s] (fused detect+transfer spin)
        i32x4 w0 = {0,0,0,0}, w1 = {0,0,0,0}, w2 = {0,0,0,0}, w3 = {0,0,0,0};
        i32x4 w4 = {0,0,0,0}, w5 = {0,0,0,0}, w6 = {0,0,0,0}, w7 = {0,0,0,0};
        const u32 exp_i = (u32)(s & 7);
        const u32* pib =
            hsl + (((size_t)(s & 3)) * 64 + bg * 16 + gr) * 512;
        while (true) {
          ISSUE8(w0, w1, w2, w3, w4, w5, w6, w7, pib);
          asm volatile("s_waitcnt vmcnt(0)"
                       : "+v"(w0), "+v"(w1), "+v"(w2), "+v"(w3), "+v"(w4),
                         "+v"(w5), "+v"(w6), "+v"(w7)::"memory");
          if (__all(TAGOK8(w0, w1, w2, w3, w4, w5, w6, w7, exp_i))) break;
        }
        STAGE_IN0(w0, w1, w2, w3, w4, w5, w6, w7);
      }
    } else {
      // ================= B-group: h[s-1] path (pure h spin) =============
      if (s > 1) {
        __builtin_amdgcn_s_setprio(1);
        i32x4 w0 = {0,0,0,0}, w1 = {0,0,0,0}, w2 = {0,0,0,0}, w3 = {0,0,0,0};
        i32x4 w4 = {0,0,0,0}, w5 = {0,0,0,0}, w6 = {0,0,0,0}, w7 = {0,0,0,0};
        const u32* phb = hsl +
            (((size_t)layer * 4 + ((s - 1) & 3)) * 64 + bg * 16 + gr) * 512;
        while (true) {
          ISSUE8(w0, w1, w2, w3, w4, w5, w6, w7, phb);
          asm volatile("s_waitcnt vmcnt(0)"
                       : "+v"(w0), "+v"(w1), "+v"(w2), "+v"(w3), "+v"(w4),
                         "+v"(w5), "+v"(w6), "+v"(w7)::"memory");
          if (__all(TAGOK8(w0, w1, w2, w3, w4, w5, w6, w7, exp_h))) break;
        }
        STAGE_H(w0, w1, w2, w3, w4, w5, w6, w7);
        __builtin_amdgcn_s_setprio(0);
      }
    }
    __syncthreads();  // B1: s_in0 + s_H staged (A and B joined; bp enforced)

    // ---- full MFMA phase: all 8 waves, roles unchanged ----
    f32x4 acc0 = {0.f, 0.f, 0.f, 0.f};
    f32x4 acc1 = {0.f, 0.f, 0.f, 0.f};
    {
      const int r16 = lane & 15, kg = lane >> 4;
#pragma unroll
      for (int kt = 0; kt < 4; ++kt) {
        int k8 = kq * 16 + kt * 4 + kg;
        bf16x8 ain = __builtin_bit_cast(
            bf16x8, *(const i32x4*)(s_in0 + r16 * 512 + ((k8 ^ (r16 & 7)) << 3)));
        acc0 = __builtin_amdgcn_mfma_f32_16x16x32_bf16(ain, wih[0][kt], acc0, 0, 0, 0);
        acc1 = __builtin_amdgcn_mfma_f32_16x16x32_bf16(ain, wih[1][kt], acc1, 0, 0, 0);
      }
      if (s > 1) {
#pragma unroll
        for (int kt = 0; kt < 4; ++kt) {
          int k8 = kq * 16 + kt * 4 + kg;
          bf16x8 ahi = __builtin_bit_cast(
              bf16x8, *(const i32x4*)(s_Hhi + r16 * 512 + ((k8 ^ (r16 & 7)) << 3)));
          bf16x8 alo = __builtin_bit_cast(
              bf16x8, *(const i32x4*)(s_Hlo + r16 * 512 + ((k8 ^ (r16 & 7)) << 3)));
          acc0 = __builtin_amdgcn_mfma_f32_16x16x32_bf16(ahi, whhh[0][kt], acc0, 0, 0, 0);
          acc0 = __builtin_amdgcn_mfma_f32_16x16x32_bf16(ahi, whhl[0][kt], acc0, 0, 0, 0);
          acc0 = __builtin_amdgcn_mfma_f32_16x16x32_bf16(alo, whhh[0][kt], acc0, 0, 0, 0);
          acc1 = __builtin_amdgcn_mfma_f32_16x16x32_bf16(ahi, whhh[1][kt], acc1, 0, 0, 0);
          acc1 = __builtin_amdgcn_mfma_f32_16x16x32_bf16(ahi, whhl[1][kt], acc1, 0, 0, 0);
          acc1 = __builtin_amdgcn_mfma_f32_16x16x32_bf16(alo, whhh[1][kt], acc1, 0, 0, 0);
        }
      }
#pragma unroll
      for (int j = 0; j < 4; ++j) {
        int m = kg * 4 + j;
        int xr = (m >> 2) & 3;
        int n0i = nh * 32 + 0 * 16 + r16;
        int n1i = nh * 32 + 1 * 16 + r16;
        s_part[kq * 1024 + m * 64 + (n0i ^ (xr << 4))] = acc0[j];
        s_part[kq * 1024 + m * 64 + (n1i ^ (xr << 4))] = acc1[j];
      }
    }
    __syncthreads();  // B3

    // ---- finals: reduce, bias, fast-tanh, pack word (hi|lo|tag), publish ----
    {
      int m = tid >> 5, na = (tid & 31) * 2;
      int xr = (m >> 2) & 3;
      float v0 = biasv0, v1 = biasv1;
#pragma unroll
      for (int q2 = 0; q2 < 4; ++q2) {
        const float2* sp =
            (const float2*)(s_part + q2 * 1024 + m * 64 + (na ^ (xr << 4)));
        float2 t = *sp;
        v0 += t.x;
        v1 += t.y;
      }
      v0 = fast_tanh(v0);
      v1 = fast_tanh(v1);
      unsigned short a0 = f2bf(v0), a1 = f2bf(v1);
      unsigned short b0 = f2bf(v0 - bf2f(a0)), b1 = f2bf(v1 - bf2f(a1));
      u32 tag = (u32)(s & 7);
      u32x2 wv;
      wv[0] = ((u32)a0 << 16) | ((u32)b0 & 0xFFF8u) | tag;
      wv[1] = ((u32)a1 << 16) | ((u32)b1 & 0xFFF8u) | tag;
      u32* dst = hsl + (((size_t)layer * 4 + (s & 3)) * 64 + bg * 16 + m) * 512 +
                 c * 64 + na;
      UC_STORE2(dst, wv);
    }
    // no drain, no flag: consumers detect via embedded tags
  }
}

__global__ void k_fc(const u32* __restrict__ h1w, const float* __restrict__ fcW,
                     const float* __restrict__ fcb, float* __restrict__ out) {
  int i = threadIdx.x;  // 512 = 64 batch x 8 classes
  int b = i >> 3, cc = i & 7;
  float acc = fcb[cc];
  const u32* ph = h1w + b * 512;
  const float* pw = fcW + cc * 512;
  for (int k = 0; k < 512; k += 4) {
    int4 w4 = *(const int4*)(ph + k);
    float4 wv = *(const float4*)(pw + k);
    acc += (bf2f((unsigned short)((u32)w4.x >> 16)) +
            bf2f((unsigned short)((u32)w4.x & 0xFFF8u))) * wv.x;
    acc += (bf2f((unsigned short)((u32)w4.y >> 16)) +
            bf2f((unsigned short)((u32)w4.y & 0xFFF8u))) * wv.y;
    acc += (bf2f((unsigned short)((u32)w4.z >> 16)) +
            bf2f((unsigned short)((u32)w4.z & 0xFFF8u))) * wv.z;
    acc += (bf2f((unsigned short)((u32)w4.w >> 16)) +
            bf2f((unsigned short)((u32)w4.w & 0xFFF8u))) * wv.w;
  }
  out[b * 8 + cc] = acc;
}

extern "C" void kernel_launch(void* const* d_in, const int* in_sizes, int n_in,
                              void* d_out, int out_size, void* d_ws, size_t ws_size,
                              hipStream_t stream) {
  const int* x = (const int*)d_in[0];
  const float* emb = (const float*)d_in[1];
  const float* Wih0 = (const float*)d_in[2];
  const float* Whh0 = (const float*)d_in[3];
  const float* bih0 = (const float*)d_in[4];
  const float* bhh0 = (const float*)d_in[5];
  const float* Wih1 = (const float*)d_in[6];
  const float* Whh1 = (const float*)d_in[7];
  const float* bih1 = (const float*)d_in[8];
  const float* bhh1 = (const float*)d_in[9];
  const float* fcW = (const float*)d_in[10];
  const float* fcb = (const float*)d_in[11];

  u32* hsl = (u32*)d_ws;  // 2 layers x 4 slots x 64 x 512 u32 = 1 MB

  hipMemsetAsync(hsl, 0, (size_t)2 * 4 * 64 * 512 * 4, stream);
  hipLaunchKernelGGL(k_rnn, dim3(64), dim3(512), 0, stream, x, emb, Wih0, Whh0,
                     bih0, bhh0, Wih1, Whh1, bih1, bhh1, hsl);
  // final h1 = step 512 -> layer1 slot (512&3)==0
  hipLaunchKernelGGL(k_fc, dim3(1), dim3(512), 0, stream,
                     hsl + (size_t)4 * 64 * 512, fcW, fcb, (float*)d_out);
}